// Round 14
// baseline (244.807 us; speedup 1.0000x reference)
//
#include <hip/hip_runtime.h>
#include <math.h>

// Qnet: per-row tiny MLP + gumbel-sigmoid straight-through gates + 5 tiny experts.
//
// Round-13 post-mortem: VALUBusy is CU-level (4 SIMDs) -> real per-SIMD VALU
// ~13% in r8; VALU was never the wall. Wall-time pins at ~123us = 2.5 TB/s
// effective HBM across r8/r10/r11/r13 regardless of issue-count changes.
// Diagnosis: working set 416MB > L3 256MB, and the 192MB of output writes
// ALLOCATE in L3, evicting the input streams every replay -> inputs re-fetch
// from HBM + write-allocate pollution caps read BW.
// This round: r11 skeleton (packed v2f row-pair, 2 rows/thread, VGPR~48) +
// r13 exp2-domain math + NONTEMPORAL stores for out/soft/hard. Outputs
// bypass L3 -> inputs (224MB) fit the 256MB L3 and persist across replays ->
// steady-state FETCH collapses; HBM ~ writes only (~197MB, floor ~35us).
// Rare flagged rows -> patch kernel = bit-exact CR-f32 numpy simulation.

constexpr float EPSF = 1e-8f;
constexpr float LN2F = 0.69314718055994531f;
constexpr float T2L  = -2.8853900817779268f;   // -2*log2(e)
constexpr float NL2E = -1.4426950408889634f;   // -log2(e)

typedef float v2f __attribute__((ext_vector_type(2)));
typedef float v4f __attribute__((ext_vector_type(4)));
static __device__ __forceinline__ v2f s2(float s) { return (v2f){s, s}; }
static __device__ __forceinline__ float fexp2(float a) { return __builtin_amdgcn_exp2f(a); }
static __device__ __forceinline__ float flog2(float a) { return __builtin_amdgcn_logf(a); }

__global__ __launch_bounds__(256) void qnet_main(
    const float* __restrict__ x,
    const float* __restrict__ u1,
    const float* __restrict__ u2,
    const float* __restrict__ fc1_w,    // [4][4]
    const float* __restrict__ fc1_b,    // [4]
    const float* __restrict__ picker_w, // [5][4]
    const float* __restrict__ picker_b, // [5]
    const float* __restrict__ ew1,      // [5][4][4]
    const float* __restrict__ eb1,      // [5][4]
    const float* __restrict__ ew2,      // [5][2][4]
    const float* __restrict__ eb2,      // [5][2]
    float* __restrict__ out_o,          // [B][2]
    float* __restrict__ hard_o,         // [B][5]
    float* __restrict__ soft_o,         // [B][5]
    unsigned* __restrict__ flag_cnt,
    unsigned* __restrict__ flag_list,
    unsigned flag_cap)
{
    const unsigned t = blockIdx.x * blockDim.x + threadIdx.x;  // rows 2t, 2t+1

    const float4* x4  = reinterpret_cast<const float4*>(x);
    const float2* u12 = reinterpret_cast<const float2*>(u1);
    const float2* u22 = reinterpret_cast<const float2*>(u2);

    const float4 xa = x4[2u * t + 0];
    const float4 xb = x4[2u * t + 1];
    v2f xp[4];
    xp[0] = (v2f){xa.x, xb.x}; xp[1] = (v2f){xa.y, xb.y};
    xp[2] = (v2f){xa.z, xb.z}; xp[3] = (v2f){xa.w, xb.w};

    float2 l1[5], l2[5];
#pragma unroll
    for (int k = 0; k < 5; ++k) {
        l1[k] = u12[5u * t + k];
        l2[k] = u22[5u * t + k];
    }
    v2f u1p[5], u2p[5];
    u1p[0] = (v2f){l1[0].x, l1[2].y}; u1p[1] = (v2f){l1[0].y, l1[3].x};
    u1p[2] = (v2f){l1[1].x, l1[3].y}; u1p[3] = (v2f){l1[1].y, l1[4].x};
    u1p[4] = (v2f){l1[2].x, l1[4].y};
    u2p[0] = (v2f){l2[0].x, l2[2].y}; u2p[1] = (v2f){l2[0].y, l2[3].x};
    u2p[2] = (v2f){l2[1].x, l2[3].y}; u2p[3] = (v2f){l2[1].y, l2[4].x};
    u2p[4] = (v2f){l2[2].x, l2[4].y};

    // h = tanh(fc1(x)) — packed FMA, exp2-folded tanh
    v2f h[4];
#pragma unroll
    for (int j = 0; j < 4; ++j) {
        v2f a = s2(fc1_b[j]);
#pragma unroll
        for (int i = 0; i < 4; ++i) a += xp[i] * s2(fc1_w[4 * j + i]);
        const v2f as = a * s2(T2L);          // -2a*log2e
        const float ex = fexp2(as.x);
        const float ey = fexp2(as.y);
        h[j] = (v2f){fmaf(2.0f, __builtin_amdgcn_rcpf(1.0f + ex), -1.0f),
                     fmaf(2.0f, __builtin_amdgcn_rcpf(1.0f + ey), -1.0f)};
    }

    v2f o0 = s2(0.0f), o1 = s2(0.0f);
    v2f softp[5], hardp[5];
    v2f rowmin = s2(1e30f);

#pragma unroll
    for (int c = 0; c < 5; ++c) {
        v2f lg = s2(picker_b[c]);
#pragma unroll
        for (int j = 0; j < 4; ++j) lg += h[j] * s2(picker_w[4 * c + j]);

        const v2f a1 = u1p[c] + s2(EPSF);
        const v2f a2 = u2p[c] + s2(EPSF);
        // t+eps = fmaf(-ln2, log2(u+eps), eps)
        const v2f t1e = (v2f){fmaf(-LN2F, flog2(a1.x), EPSF),
                              fmaf(-LN2F, flog2(a1.y), EPSF)};
        const v2f t2e = (v2f){fmaf(-LN2F, flog2(a2.x), EPSF),
                              fmaf(-LN2F, flog2(a2.y), EPSF)};
        const v2f lgs = lg * s2(NL2E);
        const v2f epv = (v2f){fexp2(lgs.x), fexp2(lgs.y)} * t1e;
        const v2f den = t2e + epv;
        const v2f sft = t2e * (v2f){__builtin_amdgcn_rcpf(den.x),
                                    __builtin_amdgcn_rcpf(den.y)};
        const v2f hrd = (v2f){(epv.x <= t2e.x) ? 1.0f : 0.0f,
                              (epv.y <= t2e.y) ? 1.0f : 0.0f};

        rowmin = __builtin_elementwise_min(
            rowmin, __builtin_elementwise_abs(sft - s2(0.5f)));

        softp[c] = sft;
        hardp[c] = hrd;

        v2f eh[4];
#pragma unroll
        for (int k = 0; k < 4; ++k) {
            v2f a = s2(eb1[4 * c + k]);
#pragma unroll
            for (int j = 0; j < 4; ++j) a += h[j] * s2(ew1[16 * c + 4 * k + j]);
            eh[k] = __builtin_elementwise_max(a, s2(0.0f));
        }
        v2f e0 = s2(eb2[2 * c + 0]);
        v2f e1 = s2(eb2[2 * c + 1]);
#pragma unroll
        for (int k = 0; k < 4; ++k) {
            e0 += eh[k] * s2(ew2[8 * c + 0 + k]);
            e1 += eh[k] * s2(ew2[8 * c + 4 + k]);
        }
        o0 += hrd * e0;
        o1 += hrd * e1;
    }

    // rare flags (soft-domain window; patch recomputes whole row)
    if (__builtin_expect(rowmin.x < 2.63e-5f, 0)) {
        unsigned mask = 0;
#pragma unroll
        for (int c = 0; c < 5; ++c) mask |= (hardp[c].x != 0.0f) ? (1u << c) : 0u;
        const unsigned slot = atomicAdd(flag_cnt, 1u);
        if (slot < flag_cap) flag_list[slot] = ((2u * t + 0) << 5) | mask;
    }
    if (__builtin_expect(rowmin.y < 2.63e-5f, 0)) {
        unsigned mask = 0;
#pragma unroll
        for (int c = 0; c < 5; ++c) mask |= (hardp[c].y != 0.0f) ? (1u << c) : 0u;
        const unsigned slot = atomicAdd(flag_cnt, 1u);
        if (slot < flag_cap) flag_list[slot] = ((2u * t + 1) << 5) | mask;
    }

    // ---- NONTEMPORAL stores: bypass L3 so inputs stay cache-resident ----
    v4f* outv = reinterpret_cast<v4f*>(out_o);
    v2f* sfv  = reinterpret_cast<v2f*>(soft_o);
    v2f* hdv  = reinterpret_cast<v2f*>(hard_o);
    __builtin_nontemporal_store((v4f){o0.x, o1.x, o0.y, o1.y}, &outv[t]);
    __builtin_nontemporal_store((v2f){softp[0].x, softp[1].x}, &sfv[5u * t + 0]);
    __builtin_nontemporal_store((v2f){softp[2].x, softp[3].x}, &sfv[5u * t + 1]);
    __builtin_nontemporal_store((v2f){softp[4].x, softp[0].y}, &sfv[5u * t + 2]);
    __builtin_nontemporal_store((v2f){softp[1].y, softp[2].y}, &sfv[5u * t + 3]);
    __builtin_nontemporal_store((v2f){softp[3].y, softp[4].y}, &sfv[5u * t + 4]);
    __builtin_nontemporal_store((v2f){hardp[0].x, hardp[1].x}, &hdv[5u * t + 0]);
    __builtin_nontemporal_store((v2f){hardp[2].x, hardp[3].x}, &hdv[5u * t + 1]);
    __builtin_nontemporal_store((v2f){hardp[4].x, hardp[0].y}, &hdv[5u * t + 2]);
    __builtin_nontemporal_store((v2f){hardp[1].y, hardp[2].y}, &hdv[5u * t + 3]);
    __builtin_nontemporal_store((v2f){hardp[3].y, hardp[4].y}, &hdv[5u * t + 4]);
}

// ---- rare patch kernel: bit-exact CR-f32 numpy simulation (authority) ----
__global__ __launch_bounds__(256) void qnet_patch(
    const float* __restrict__ x,
    const float* __restrict__ u1,
    const float* __restrict__ u2,
    const float* __restrict__ fc1_w,
    const float* __restrict__ fc1_b,
    const float* __restrict__ picker_w,
    const float* __restrict__ picker_b,
    const float* __restrict__ ew1,
    const float* __restrict__ eb1,
    const float* __restrict__ ew2,
    const float* __restrict__ eb2,
    float* __restrict__ out_o,
    float* __restrict__ hard_o,
    float* __restrict__ soft_o,
    const unsigned* __restrict__ flag_cnt,
    const unsigned* __restrict__ flag_list,
    unsigned flag_cap)
{
    const unsigned n = min(flag_cnt[0], flag_cap);
    const unsigned stride = gridDim.x * blockDim.x;
    for (unsigned i = blockIdx.x * blockDim.x + threadIdx.x; i < n; i += stride) {
        const unsigned e = flag_list[i];
        const unsigned row = e >> 5;
        const unsigned fmask = e & 31u;

        const float4 xv = reinterpret_cast<const float4*>(x)[row];
        const float xr[4] = {xv.x, xv.y, xv.z, xv.w};

        float h32[4];
#pragma unroll
        for (int j = 0; j < 4; ++j) {
            float acc = 0.0f;
#pragma unroll
            for (int i2 = 0; i2 < 4; ++i2)
                acc = fmaf(xr[i2], fc1_w[4 * j + i2], acc);
            const float hpre = acc + fc1_b[j];
            h32[j] = (float)tanh((double)hpre);
        }

        float dout0 = 0.0f, dout1 = 0.0f;
#pragma unroll
        for (int c = 0; c < 5; ++c) {
            const unsigned idx5 = row * 5u + c;
            const float uu1 = u1[idx5];
            const float uu2 = u2[idx5];

            float lacc = 0.0f;
#pragma unroll
            for (int j = 0; j < 4; ++j)
                lacc = fmaf(h32[j], picker_w[4 * c + j], lacc);
            const float lg32 = lacc + picker_b[c];
            const float a1 = uu1 + EPSF;
            const float l1 = (float)log((double)a1);
            const float b1 = (-l1) + EPSF;
            const float g1s = -((float)log((double)b1));
            const float a2 = uu2 + EPSF;
            const float l2 = (float)log((double)a2);
            const float b2 = (-l2) + EPSF;
            const float g2s = -((float)log((double)b2));
            const float dd = g1s - g2s;
            const float z32 = lg32 + dd;
            const float e32 = (float)exp((double)(-z32));
            const float den = 1.0f + e32;
            const float s32 = 1.0f / den;
            const float crhard = (s32 >= 0.5f) ? 1.0f : 0.0f;
            const float fasthard = ((fmask >> c) & 1u) ? 1.0f : 0.0f;

            soft_o[idx5] = s32;
            hard_o[idx5] = crhard;

            if (crhard != fasthard) {
                float eh[4];
#pragma unroll
                for (int k = 0; k < 4; ++k) {
                    float a = eb1[4 * c + k];
#pragma unroll
                    for (int j = 0; j < 4; ++j) a += h32[j] * ew1[16 * c + 4 * k + j];
                    eh[k] = fmaxf(a, 0.0f);
                }
                float e0 = eb2[2 * c + 0];
                float e1 = eb2[2 * c + 1];
#pragma unroll
                for (int k = 0; k < 4; ++k) {
                    e0 += eh[k] * ew2[8 * c + 0 + k];
                    e1 += eh[k] * ew2[8 * c + 4 + k];
                }
                const float d = crhard - fasthard;
                dout0 += d * e0;
                dout1 += d * e1;
            }
        }
        if (dout0 != 0.0f) atomicAdd(&out_o[2u * row + 0], dout0);
        if (dout1 != 0.0f) atomicAdd(&out_o[2u * row + 1], dout1);
    }
}

extern "C" void kernel_launch(void* const* d_in, const int* in_sizes, int n_in,
                              void* d_out, int out_size, void* d_ws, size_t ws_size,
                              hipStream_t stream) {
    const float* x        = (const float*)d_in[0];
    const float* u1       = (const float*)d_in[1];
    const float* u2       = (const float*)d_in[2];
    const float* fc1_w    = (const float*)d_in[3];
    const float* fc1_b    = (const float*)d_in[4];
    const float* picker_w = (const float*)d_in[5];
    const float* picker_b = (const float*)d_in[6];
    const float* ew1      = (const float*)d_in[7];
    const float* eb1      = (const float*)d_in[8];
    const float* ew2      = (const float*)d_in[9];
    const float* eb2      = (const float*)d_in[10];

    const long long B = in_sizes[0] / 4;        // rows
    float* out  = (float*)d_out;                // [B][2]
    float* hard = out + (size_t)B * 2;          // [B][5]
    float* soft = hard + (size_t)B * 5;         // [B][5]

    unsigned* flag_cnt  = (unsigned*)d_ws;
    unsigned* flag_list = flag_cnt + 1;
    const unsigned flag_cap = (unsigned)(ws_size / 4 - 1);

    (void)hipMemsetAsync(d_ws, 0, 4, stream);   // zero the counter (capturable)

    const int threads = 256;
    const long long nthreads = B / 2;           // 2 rows per thread
    const int blocks = (int)((nthreads + threads - 1) / threads);
    qnet_main<<<blocks, threads, 0, stream>>>(
        x, u1, u2, fc1_w, fc1_b, picker_w, picker_b,
        ew1, eb1, ew2, eb2, out, hard, soft,
        flag_cnt, flag_list, flag_cap);

    qnet_patch<<<128, 256, 0, stream>>>(
        x, u1, u2, fc1_w, fc1_b, picker_w, picker_b,
        ew1, eb1, ew2, eb2, out, hard, soft,
        flag_cnt, flag_list, flag_cap);
}

// Round 15
// 108.032 us; speedup vs baseline: 2.2661x; 2.2661x over previous
//
#include <hip/hip_runtime.h>
#include <math.h>

// Qnet: per-row tiny MLP + gumbel-sigmoid straight-through gates + 5 tiny experts.
//
// Round-14 post-mortem: nontemporal stores -> WRITE_SIZE 197->550MB (8B NT
// stores skip L2 write-coalescing; partial-sector HBM writes). Reverted.
// Confirmed frame: the 123us plateau is TRANSACTION-rate, not bytes — the
// 40B-strided float2 u/soft/hard instructions scatter into ~64 sub-sector
// L2 transactions each (~1300/wave vs ~400 coalesced).
// This round: LDS transpose-staging for u1/u2/x/soft/hard ONLY (r7's idea)
// with weights kept in SGPRs (r8's lesson — r7 died on ~195 ds weight
// re-reads/row). Block = 512 rows:
//   stage:  coalesced float4 loads -> LDS (u1 640, u2 640, x 512 float4)
//   compute: thread reads its 2 rows from LDS (contiguous 40B -> b64 reads,
//            4-way conflict = 1.58x, LDS pipe is otherwise idle);
//            r11/r13 packed-v2f core; soft/hard overwrite u1/u2 LDS in place
//   store:  cooperative coalesced float4 stores (soft/hard), direct out
// Global instrs/thread: 13 coalesced (was 23 strided). LDS 28.7KB -> 5
// blocks/CU. Rare flagged rows -> patch kernel = bit-exact CR-f32 numpy
// simulation (correctness authority near the gate boundary).

constexpr float EPSF = 1e-8f;
constexpr float LN2F = 0.69314718055994531f;
constexpr float T2L  = -2.8853900817779268f;   // -2*log2(e)
constexpr float NL2E = -1.4426950408889634f;   // -log2(e)

typedef float v2f __attribute__((ext_vector_type(2)));
static __device__ __forceinline__ v2f s2(float s) { return (v2f){s, s}; }
static __device__ __forceinline__ float fexp2(float a) { return __builtin_amdgcn_exp2f(a); }
static __device__ __forceinline__ float flog2(float a) { return __builtin_amdgcn_logf(a); }

__global__ __launch_bounds__(256) void qnet_main(
    const float* __restrict__ x,
    const float* __restrict__ u1,
    const float* __restrict__ u2,
    const float* __restrict__ fc1_w,    // [4][4]
    const float* __restrict__ fc1_b,    // [4]
    const float* __restrict__ picker_w, // [5][4]
    const float* __restrict__ picker_b, // [5]
    const float* __restrict__ ew1,      // [5][4][4]
    const float* __restrict__ eb1,      // [5][4]
    const float* __restrict__ ew2,      // [5][2][4]
    const float* __restrict__ eb2,      // [5][2]
    float* __restrict__ out_o,          // [B][2]
    float* __restrict__ hard_o,         // [B][5]
    float* __restrict__ soft_o,         // [B][5]
    unsigned* __restrict__ flag_cnt,
    unsigned* __restrict__ flag_list,
    unsigned flag_cap)
{
    __shared__ float4 s_u1[640];   // 512 rows * 5 floats; becomes soft
    __shared__ float4 s_u2[640];   // becomes hard
    __shared__ float4 s_x[512];

    const unsigned tid  = threadIdx.x;
    const unsigned row0 = blockIdx.x * 512u;
    const unsigned b5   = blockIdx.x * 640u;   // float4 base into u/soft/hard

    // ---- stage: coalesced global -> LDS ----
    {
        const float4* u14 = reinterpret_cast<const float4*>(u1) + b5;
        const float4* u24 = reinterpret_cast<const float4*>(u2) + b5;
        const float4* x4g = reinterpret_cast<const float4*>(x) + row0;
        s_u1[tid]        = u14[tid];
        s_u1[tid + 256]  = u14[tid + 256];
        s_u2[tid]        = u24[tid];
        s_u2[tid + 256]  = u24[tid + 256];
        s_x[tid]         = x4g[tid];
        s_x[tid + 256]   = x4g[tid + 256];
        if (tid < 128) {
            s_u1[tid + 512] = u14[tid + 512];
            s_u2[tid + 512] = u24[tid + 512];
        }
    }
    __syncthreads();

    // ---- per-thread: rows 2*tid, 2*tid+1 within the block ----
    float* s_u1f = reinterpret_cast<float*>(s_u1);
    float* s_u2f = reinterpret_cast<float*>(s_u2);

    float us1[10], us2[10];
#pragma unroll
    for (int j = 0; j < 10; ++j) {
        us1[j] = s_u1f[10u * tid + j];   // us1[0..4]=row A gates, [5..9]=row B
        us2[j] = s_u2f[10u * tid + j];
    }
    const float4 xa = s_x[2u * tid + 0];
    const float4 xb = s_x[2u * tid + 1];

    v2f xp[4];
    xp[0] = (v2f){xa.x, xb.x}; xp[1] = (v2f){xa.y, xb.y};
    xp[2] = (v2f){xa.z, xb.z}; xp[3] = (v2f){xa.w, xb.w};

    // h = tanh(fc1(x)) — packed FMA, exp2-folded tanh; weights via s_load
    v2f h[4];
#pragma unroll
    for (int j = 0; j < 4; ++j) {
        v2f a = s2(fc1_b[j]);
#pragma unroll
        for (int i = 0; i < 4; ++i) a += xp[i] * s2(fc1_w[4 * j + i]);
        const v2f as = a * s2(T2L);
        const float ex = fexp2(as.x);
        const float ey = fexp2(as.y);
        h[j] = (v2f){fmaf(2.0f, __builtin_amdgcn_rcpf(1.0f + ex), -1.0f),
                     fmaf(2.0f, __builtin_amdgcn_rcpf(1.0f + ey), -1.0f)};
    }

    v2f o0 = s2(0.0f), o1 = s2(0.0f);
    v2f rowmin = s2(1e30f);
    unsigned maskA = 0, maskB = 0;

#pragma unroll
    for (int c = 0; c < 5; ++c) {
        v2f lg = s2(picker_b[c]);
#pragma unroll
        for (int j = 0; j < 4; ++j) lg += h[j] * s2(picker_w[4 * c + j]);

        const v2f a1 = (v2f){us1[c], us1[5 + c]} + s2(EPSF);
        const v2f a2 = (v2f){us2[c], us2[5 + c]} + s2(EPSF);
        // t+eps = fmaf(-ln2, log2(u+eps), eps)
        const v2f t1e = (v2f){fmaf(-LN2F, flog2(a1.x), EPSF),
                              fmaf(-LN2F, flog2(a1.y), EPSF)};
        const v2f t2e = (v2f){fmaf(-LN2F, flog2(a2.x), EPSF),
                              fmaf(-LN2F, flog2(a2.y), EPSF)};
        const v2f lgs = lg * s2(NL2E);
        const v2f epv = (v2f){fexp2(lgs.x), fexp2(lgs.y)} * t1e;
        const v2f den = t2e + epv;
        const v2f sft = t2e * (v2f){__builtin_amdgcn_rcpf(den.x),
                                    __builtin_amdgcn_rcpf(den.y)};
        const v2f hrd = (v2f){(epv.x <= t2e.x) ? 1.0f : 0.0f,
                              (epv.y <= t2e.y) ? 1.0f : 0.0f};

        rowmin = __builtin_elementwise_min(
            rowmin, __builtin_elementwise_abs(sft - s2(0.5f)));
        maskA |= (hrd.x != 0.0f) ? (1u << c) : 0u;
        maskB |= (hrd.y != 0.0f) ? (1u << c) : 0u;

        us1[c] = sft.x; us1[5 + c] = sft.y;   // in place: u1 -> soft
        us2[c] = hrd.x; us2[5 + c] = hrd.y;   // in place: u2 -> hard

        v2f eh[4];
#pragma unroll
        for (int k = 0; k < 4; ++k) {
            v2f a = s2(eb1[4 * c + k]);
#pragma unroll
            for (int j = 0; j < 4; ++j) a += h[j] * s2(ew1[16 * c + 4 * k + j]);
            eh[k] = __builtin_elementwise_max(a, s2(0.0f));
        }
        v2f e0 = s2(eb2[2 * c + 0]);
        v2f e1 = s2(eb2[2 * c + 1]);
#pragma unroll
        for (int k = 0; k < 4; ++k) {
            e0 += eh[k] * s2(ew2[8 * c + 0 + k]);
            e1 += eh[k] * s2(ew2[8 * c + 4 + k]);
        }
        o0 += hrd * e0;
        o1 += hrd * e1;
    }

    // rare flags (soft-domain window; patch recomputes the whole row)
    if (__builtin_expect(rowmin.x < 2.63e-5f, 0)) {
        const unsigned slot = atomicAdd(flag_cnt, 1u);
        if (slot < flag_cap) flag_list[slot] = ((row0 + 2u * tid + 0) << 5) | maskA;
    }
    if (__builtin_expect(rowmin.y < 2.63e-5f, 0)) {
        const unsigned slot = atomicAdd(flag_cnt, 1u);
        if (slot < flag_cap) flag_list[slot] = ((row0 + 2u * tid + 1) << 5) | maskB;
    }

    // write soft/hard back into LDS (in place of u1/u2)
#pragma unroll
    for (int j = 0; j < 10; ++j) {
        s_u1f[10u * tid + j] = us1[j];
        s_u2f[10u * tid + j] = us2[j];
    }

    // out store: float4 covers 2 rows -> index blockIdx*256 + tid (coalesced)
    reinterpret_cast<float4*>(out_o)[blockIdx.x * 256u + tid] =
        make_float4(o0.x, o1.x, o0.y, o1.y);

    __syncthreads();

    // ---- cooperative coalesced LDS -> global stores ----
    {
        float4* soft4 = reinterpret_cast<float4*>(soft_o) + b5;
        float4* hard4 = reinterpret_cast<float4*>(hard_o) + b5;
        soft4[tid]       = s_u1[tid];
        soft4[tid + 256] = s_u1[tid + 256];
        hard4[tid]       = s_u2[tid];
        hard4[tid + 256] = s_u2[tid + 256];
        if (tid < 128) {
            soft4[tid + 512] = s_u1[tid + 512];
            hard4[tid + 512] = s_u2[tid + 512];
        }
    }
}

// ---- rare patch kernel: bit-exact CR-f32 numpy simulation (authority) ----
__global__ __launch_bounds__(256) void qnet_patch(
    const float* __restrict__ x,
    const float* __restrict__ u1,
    const float* __restrict__ u2,
    const float* __restrict__ fc1_w,
    const float* __restrict__ fc1_b,
    const float* __restrict__ picker_w,
    const float* __restrict__ picker_b,
    const float* __restrict__ ew1,
    const float* __restrict__ eb1,
    const float* __restrict__ ew2,
    const float* __restrict__ eb2,
    float* __restrict__ out_o,
    float* __restrict__ hard_o,
    float* __restrict__ soft_o,
    const unsigned* __restrict__ flag_cnt,
    const unsigned* __restrict__ flag_list,
    unsigned flag_cap)
{
    const unsigned n = min(flag_cnt[0], flag_cap);
    const unsigned stride = gridDim.x * blockDim.x;
    for (unsigned i = blockIdx.x * blockDim.x + threadIdx.x; i < n; i += stride) {
        const unsigned e = flag_list[i];
        const unsigned row = e >> 5;
        const unsigned fmask = e & 31u;

        const float4 xv = reinterpret_cast<const float4*>(x)[row];
        const float xr[4] = {xv.x, xv.y, xv.z, xv.w};

        float h32[4];
#pragma unroll
        for (int j = 0; j < 4; ++j) {
            float acc = 0.0f;
#pragma unroll
            for (int i2 = 0; i2 < 4; ++i2)
                acc = fmaf(xr[i2], fc1_w[4 * j + i2], acc);
            const float hpre = acc + fc1_b[j];
            h32[j] = (float)tanh((double)hpre);
        }

        float dout0 = 0.0f, dout1 = 0.0f;
#pragma unroll
        for (int c = 0; c < 5; ++c) {
            const unsigned idx5 = row * 5u + c;
            const float uu1 = u1[idx5];
            const float uu2 = u2[idx5];

            float lacc = 0.0f;
#pragma unroll
            for (int j = 0; j < 4; ++j)
                lacc = fmaf(h32[j], picker_w[4 * c + j], lacc);
            const float lg32 = lacc + picker_b[c];
            const float a1 = uu1 + EPSF;
            const float l1 = (float)log((double)a1);
            const float b1 = (-l1) + EPSF;
            const float g1s = -((float)log((double)b1));
            const float a2 = uu2 + EPSF;
            const float l2 = (float)log((double)a2);
            const float b2 = (-l2) + EPSF;
            const float g2s = -((float)log((double)b2));
            const float dd = g1s - g2s;
            const float z32 = lg32 + dd;
            const float e32 = (float)exp((double)(-z32));
            const float den = 1.0f + e32;
            const float s32 = 1.0f / den;
            const float crhard = (s32 >= 0.5f) ? 1.0f : 0.0f;
            const float fasthard = ((fmask >> c) & 1u) ? 1.0f : 0.0f;

            soft_o[idx5] = s32;
            hard_o[idx5] = crhard;

            if (crhard != fasthard) {
                float eh[4];
#pragma unroll
                for (int k = 0; k < 4; ++k) {
                    float a = eb1[4 * c + k];
#pragma unroll
                    for (int j = 0; j < 4; ++j) a += h32[j] * ew1[16 * c + 4 * k + j];
                    eh[k] = fmaxf(a, 0.0f);
                }
                float e0 = eb2[2 * c + 0];
                float e1 = eb2[2 * c + 1];
#pragma unroll
                for (int k = 0; k < 4; ++k) {
                    e0 += eh[k] * ew2[8 * c + 0 + k];
                    e1 += eh[k] * ew2[8 * c + 4 + k];
                }
                const float d = crhard - fasthard;
                dout0 += d * e0;
                dout1 += d * e1;
            }
        }
        if (dout0 != 0.0f) atomicAdd(&out_o[2u * row + 0], dout0);
        if (dout1 != 0.0f) atomicAdd(&out_o[2u * row + 1], dout1);
    }
}

extern "C" void kernel_launch(void* const* d_in, const int* in_sizes, int n_in,
                              void* d_out, int out_size, void* d_ws, size_t ws_size,
                              hipStream_t stream) {
    const float* x        = (const float*)d_in[0];
    const float* u1       = (const float*)d_in[1];
    const float* u2       = (const float*)d_in[2];
    const float* fc1_w    = (const float*)d_in[3];
    const float* fc1_b    = (const float*)d_in[4];
    const float* picker_w = (const float*)d_in[5];
    const float* picker_b = (const float*)d_in[6];
    const float* ew1      = (const float*)d_in[7];
    const float* eb1      = (const float*)d_in[8];
    const float* ew2      = (const float*)d_in[9];
    const float* eb2      = (const float*)d_in[10];

    const long long B = in_sizes[0] / 4;        // rows
    float* out  = (float*)d_out;                // [B][2]
    float* hard = out + (size_t)B * 2;          // [B][5]
    float* soft = hard + (size_t)B * 5;         // [B][5]

    unsigned* flag_cnt  = (unsigned*)d_ws;
    unsigned* flag_list = flag_cnt + 1;
    const unsigned flag_cap = (unsigned)(ws_size / 4 - 1);

    (void)hipMemsetAsync(d_ws, 0, 4, stream);   // zero the counter (capturable)

    const int threads = 256;
    const int blocks = (int)(B / 512);          // 512 rows per block
    qnet_main<<<blocks, threads, 0, stream>>>(
        x, u1, u2, fc1_w, fc1_b, picker_w, picker_b,
        ew1, eb1, ew2, eb2, out, hard, soft,
        flag_cnt, flag_list, flag_cap);

    qnet_patch<<<128, 256, 0, stream>>>(
        x, u1, u2, fc1_w, fc1_b, picker_w, picker_b,
        ew1, eb1, ew2, eb2, out, hard, soft,
        flag_cnt, flag_list, flag_cap);
}

// Round 16
// 92.154 us; speedup vs baseline: 2.6565x; 1.1723x over previous
//
#include <hip/hip_runtime.h>
#include <math.h>

// Qnet: per-row tiny MLP + gumbel-sigmoid straight-through gates + 5 tiny experts.
//
// Round-15 post-mortem: LDS transpose-staging -> 108us (best), FETCH 115MB,
// WRITE 197MB, 2.6 TB/s effective. Remaining 2x to the ~65us mixed-BW floor:
// output writes ALLOCATE in L2/L3 and evict the 224MB input set (FETCH=115MB
// = half the inputs re-fetched per replay). r14's NT failure was the 40B
// STRIDE (partial-sector writes, 2.8x amplification) — r15's cooperative
// float4 stores fill whole 64B lines, so NT is now safe.
// This round, ONE change: nontemporal stores on the three coalesced output
// streams (soft/hard cooperative, out direct). Outputs bypass L2/MALL ->
// inputs stay L3-resident across graph replays -> FETCH collapses.
// Tripwire: WRITE > 250MB = amplification (revert); FETCH unchanged = nt
// doesn't bypass MALL on gfx950 (plateau).

constexpr float EPSF = 1e-8f;
constexpr float LN2F = 0.69314718055994531f;
constexpr float T2L  = -2.8853900817779268f;   // -2*log2(e)
constexpr float NL2E = -1.4426950408889634f;   // -log2(e)

typedef float v2f __attribute__((ext_vector_type(2)));
typedef float v4f __attribute__((ext_vector_type(4)));
static __device__ __forceinline__ v2f s2(float s) { return (v2f){s, s}; }
static __device__ __forceinline__ float fexp2(float a) { return __builtin_amdgcn_exp2f(a); }
static __device__ __forceinline__ float flog2(float a) { return __builtin_amdgcn_logf(a); }

__global__ __launch_bounds__(256) void qnet_main(
    const float* __restrict__ x,
    const float* __restrict__ u1,
    const float* __restrict__ u2,
    const float* __restrict__ fc1_w,    // [4][4]
    const float* __restrict__ fc1_b,    // [4]
    const float* __restrict__ picker_w, // [5][4]
    const float* __restrict__ picker_b, // [5]
    const float* __restrict__ ew1,      // [5][4][4]
    const float* __restrict__ eb1,      // [5][4]
    const float* __restrict__ ew2,      // [5][2][4]
    const float* __restrict__ eb2,      // [5][2]
    float* __restrict__ out_o,          // [B][2]
    float* __restrict__ hard_o,         // [B][5]
    float* __restrict__ soft_o,         // [B][5]
    unsigned* __restrict__ flag_cnt,
    unsigned* __restrict__ flag_list,
    unsigned flag_cap)
{
    __shared__ float4 s_u1[640];   // 512 rows * 5 floats; becomes soft
    __shared__ float4 s_u2[640];   // becomes hard
    __shared__ float4 s_x[512];

    const unsigned tid  = threadIdx.x;
    const unsigned row0 = blockIdx.x * 512u;
    const unsigned b5   = blockIdx.x * 640u;   // float4 base into u/soft/hard

    // ---- stage: coalesced global -> LDS ----
    {
        const float4* u14 = reinterpret_cast<const float4*>(u1) + b5;
        const float4* u24 = reinterpret_cast<const float4*>(u2) + b5;
        const float4* x4g = reinterpret_cast<const float4*>(x) + row0;
        s_u1[tid]        = u14[tid];
        s_u1[tid + 256]  = u14[tid + 256];
        s_u2[tid]        = u24[tid];
        s_u2[tid + 256]  = u24[tid + 256];
        s_x[tid]         = x4g[tid];
        s_x[tid + 256]   = x4g[tid + 256];
        if (tid < 128) {
            s_u1[tid + 512] = u14[tid + 512];
            s_u2[tid + 512] = u24[tid + 512];
        }
    }
    __syncthreads();

    // ---- per-thread: rows 2*tid, 2*tid+1 within the block ----
    float* s_u1f = reinterpret_cast<float*>(s_u1);
    float* s_u2f = reinterpret_cast<float*>(s_u2);

    float us1[10], us2[10];
#pragma unroll
    for (int j = 0; j < 10; ++j) {
        us1[j] = s_u1f[10u * tid + j];   // us1[0..4]=row A gates, [5..9]=row B
        us2[j] = s_u2f[10u * tid + j];
    }
    const float4 xa = s_x[2u * tid + 0];
    const float4 xb = s_x[2u * tid + 1];

    v2f xp[4];
    xp[0] = (v2f){xa.x, xb.x}; xp[1] = (v2f){xa.y, xb.y};
    xp[2] = (v2f){xa.z, xb.z}; xp[3] = (v2f){xa.w, xb.w};

    // h = tanh(fc1(x)) — packed FMA, exp2-folded tanh; weights via s_load
    v2f h[4];
#pragma unroll
    for (int j = 0; j < 4; ++j) {
        v2f a = s2(fc1_b[j]);
#pragma unroll
        for (int i = 0; i < 4; ++i) a += xp[i] * s2(fc1_w[4 * j + i]);
        const v2f as = a * s2(T2L);
        const float ex = fexp2(as.x);
        const float ey = fexp2(as.y);
        h[j] = (v2f){fmaf(2.0f, __builtin_amdgcn_rcpf(1.0f + ex), -1.0f),
                     fmaf(2.0f, __builtin_amdgcn_rcpf(1.0f + ey), -1.0f)};
    }

    v2f o0 = s2(0.0f), o1 = s2(0.0f);
    v2f rowmin = s2(1e30f);
    unsigned maskA = 0, maskB = 0;

#pragma unroll
    for (int c = 0; c < 5; ++c) {
        v2f lg = s2(picker_b[c]);
#pragma unroll
        for (int j = 0; j < 4; ++j) lg += h[j] * s2(picker_w[4 * c + j]);

        const v2f a1 = (v2f){us1[c], us1[5 + c]} + s2(EPSF);
        const v2f a2 = (v2f){us2[c], us2[5 + c]} + s2(EPSF);
        // t+eps = fmaf(-ln2, log2(u+eps), eps)
        const v2f t1e = (v2f){fmaf(-LN2F, flog2(a1.x), EPSF),
                              fmaf(-LN2F, flog2(a1.y), EPSF)};
        const v2f t2e = (v2f){fmaf(-LN2F, flog2(a2.x), EPSF),
                              fmaf(-LN2F, flog2(a2.y), EPSF)};
        const v2f lgs = lg * s2(NL2E);
        const v2f epv = (v2f){fexp2(lgs.x), fexp2(lgs.y)} * t1e;
        const v2f den = t2e + epv;
        const v2f sft = t2e * (v2f){__builtin_amdgcn_rcpf(den.x),
                                    __builtin_amdgcn_rcpf(den.y)};
        const v2f hrd = (v2f){(epv.x <= t2e.x) ? 1.0f : 0.0f,
                              (epv.y <= t2e.y) ? 1.0f : 0.0f};

        rowmin = __builtin_elementwise_min(
            rowmin, __builtin_elementwise_abs(sft - s2(0.5f)));
        maskA |= (hrd.x != 0.0f) ? (1u << c) : 0u;
        maskB |= (hrd.y != 0.0f) ? (1u << c) : 0u;

        us1[c] = sft.x; us1[5 + c] = sft.y;   // in place: u1 -> soft
        us2[c] = hrd.x; us2[5 + c] = hrd.y;   // in place: u2 -> hard

        v2f eh[4];
#pragma unroll
        for (int k = 0; k < 4; ++k) {
            v2f a = s2(eb1[4 * c + k]);
#pragma unroll
            for (int j = 0; j < 4; ++j) a += h[j] * s2(ew1[16 * c + 4 * k + j]);
            eh[k] = __builtin_elementwise_max(a, s2(0.0f));
        }
        v2f e0 = s2(eb2[2 * c + 0]);
        v2f e1 = s2(eb2[2 * c + 1]);
#pragma unroll
        for (int k = 0; k < 4; ++k) {
            e0 += eh[k] * s2(ew2[8 * c + 0 + k]);
            e1 += eh[k] * s2(ew2[8 * c + 4 + k]);
        }
        o0 += hrd * e0;
        o1 += hrd * e1;
    }

    // rare flags (soft-domain window; patch recomputes the whole row)
    if (__builtin_expect(rowmin.x < 2.63e-5f, 0)) {
        const unsigned slot = atomicAdd(flag_cnt, 1u);
        if (slot < flag_cap) flag_list[slot] = ((row0 + 2u * tid + 0) << 5) | maskA;
    }
    if (__builtin_expect(rowmin.y < 2.63e-5f, 0)) {
        const unsigned slot = atomicAdd(flag_cnt, 1u);
        if (slot < flag_cap) flag_list[slot] = ((row0 + 2u * tid + 1) << 5) | maskB;
    }

    // write soft/hard back into LDS (in place of u1/u2)
#pragma unroll
    for (int j = 0; j < 10; ++j) {
        s_u1f[10u * tid + j] = us1[j];
        s_u2f[10u * tid + j] = us2[j];
    }

    // out store: coalesced float4, nontemporal (full lines across 4 lanes)
    {
        v4f* outv = reinterpret_cast<v4f*>(out_o);
        __builtin_nontemporal_store((v4f){o0.x, o1.x, o0.y, o1.y},
                                    &outv[blockIdx.x * 256u + tid]);
    }

    __syncthreads();

    // ---- cooperative coalesced LDS -> global stores, nontemporal ----
    {
        v4f* soft4 = reinterpret_cast<v4f*>(soft_o) + b5;
        v4f* hard4 = reinterpret_cast<v4f*>(hard_o) + b5;
        const v4f* l1 = reinterpret_cast<const v4f*>(s_u1);
        const v4f* l2 = reinterpret_cast<const v4f*>(s_u2);
        __builtin_nontemporal_store(l1[tid],        &soft4[tid]);
        __builtin_nontemporal_store(l1[tid + 256],  &soft4[tid + 256]);
        __builtin_nontemporal_store(l2[tid],        &hard4[tid]);
        __builtin_nontemporal_store(l2[tid + 256],  &hard4[tid + 256]);
        if (tid < 128) {
            __builtin_nontemporal_store(l1[tid + 512], &soft4[tid + 512]);
            __builtin_nontemporal_store(l2[tid + 512], &hard4[tid + 512]);
        }
    }
}

// ---- rare patch kernel: bit-exact CR-f32 numpy simulation (authority) ----
__global__ __launch_bounds__(256) void qnet_patch(
    const float* __restrict__ x,
    const float* __restrict__ u1,
    const float* __restrict__ u2,
    const float* __restrict__ fc1_w,
    const float* __restrict__ fc1_b,
    const float* __restrict__ picker_w,
    const float* __restrict__ picker_b,
    const float* __restrict__ ew1,
    const float* __restrict__ eb1,
    const float* __restrict__ ew2,
    const float* __restrict__ eb2,
    float* __restrict__ out_o,
    float* __restrict__ hard_o,
    float* __restrict__ soft_o,
    const unsigned* __restrict__ flag_cnt,
    const unsigned* __restrict__ flag_list,
    unsigned flag_cap)
{
    const unsigned n = min(flag_cnt[0], flag_cap);
    const unsigned stride = gridDim.x * blockDim.x;
    for (unsigned i = blockIdx.x * blockDim.x + threadIdx.x; i < n; i += stride) {
        const unsigned e = flag_list[i];
        const unsigned row = e >> 5;
        const unsigned fmask = e & 31u;

        const float4 xv = reinterpret_cast<const float4*>(x)[row];
        const float xr[4] = {xv.x, xv.y, xv.z, xv.w};

        float h32[4];
#pragma unroll
        for (int j = 0; j < 4; ++j) {
            float acc = 0.0f;
#pragma unroll
            for (int i2 = 0; i2 < 4; ++i2)
                acc = fmaf(xr[i2], fc1_w[4 * j + i2], acc);
            const float hpre = acc + fc1_b[j];
            h32[j] = (float)tanh((double)hpre);
        }

        float dout0 = 0.0f, dout1 = 0.0f;
#pragma unroll
        for (int c = 0; c < 5; ++c) {
            const unsigned idx5 = row * 5u + c;
            const float uu1 = u1[idx5];
            const float uu2 = u2[idx5];

            float lacc = 0.0f;
#pragma unroll
            for (int j = 0; j < 4; ++j)
                lacc = fmaf(h32[j], picker_w[4 * c + j], lacc);
            const float lg32 = lacc + picker_b[c];
            const float a1 = uu1 + EPSF;
            const float l1 = (float)log((double)a1);
            const float b1 = (-l1) + EPSF;
            const float g1s = -((float)log((double)b1));
            const float a2 = uu2 + EPSF;
            const float l2 = (float)log((double)a2);
            const float b2 = (-l2) + EPSF;
            const float g2s = -((float)log((double)b2));
            const float dd = g1s - g2s;
            const float z32 = lg32 + dd;
            const float e32 = (float)exp((double)(-z32));
            const float den = 1.0f + e32;
            const float s32 = 1.0f / den;
            const float crhard = (s32 >= 0.5f) ? 1.0f : 0.0f;
            const float fasthard = ((fmask >> c) & 1u) ? 1.0f : 0.0f;

            soft_o[idx5] = s32;
            hard_o[idx5] = crhard;

            if (crhard != fasthard) {
                float eh[4];
#pragma unroll
                for (int k = 0; k < 4; ++k) {
                    float a = eb1[4 * c + k];
#pragma unroll
                    for (int j = 0; j < 4; ++j) a += h32[j] * ew1[16 * c + 4 * k + j];
                    eh[k] = fmaxf(a, 0.0f);
                }
                float e0 = eb2[2 * c + 0];
                float e1 = eb2[2 * c + 1];
#pragma unroll
                for (int k = 0; k < 4; ++k) {
                    e0 += eh[k] * ew2[8 * c + 0 + k];
                    e1 += eh[k] * ew2[8 * c + 4 + k];
                }
                const float d = crhard - fasthard;
                dout0 += d * e0;
                dout1 += d * e1;
            }
        }
        if (dout0 != 0.0f) atomicAdd(&out_o[2u * row + 0], dout0);
        if (dout1 != 0.0f) atomicAdd(&out_o[2u * row + 1], dout1);
    }
}

extern "C" void kernel_launch(void* const* d_in, const int* in_sizes, int n_in,
                              void* d_out, int out_size, void* d_ws, size_t ws_size,
                              hipStream_t stream) {
    const float* x        = (const float*)d_in[0];
    const float* u1       = (const float*)d_in[1];
    const float* u2       = (const float*)d_in[2];
    const float* fc1_w    = (const float*)d_in[3];
    const float* fc1_b    = (const float*)d_in[4];
    const float* picker_w = (const float*)d_in[5];
    const float* picker_b = (const float*)d_in[6];
    const float* ew1      = (const float*)d_in[7];
    const float* eb1      = (const float*)d_in[8];
    const float* ew2      = (const float*)d_in[9];
    const float* eb2      = (const float*)d_in[10];

    const long long B = in_sizes[0] / 4;        // rows
    float* out  = (float*)d_out;                // [B][2]
    float* hard = out + (size_t)B * 2;          // [B][5]
    float* soft = hard + (size_t)B * 5;         // [B][5]

    unsigned* flag_cnt  = (unsigned*)d_ws;
    unsigned* flag_list = flag_cnt + 1;
    const unsigned flag_cap = (unsigned)(ws_size / 4 - 1);

    (void)hipMemsetAsync(d_ws, 0, 4, stream);   // zero the counter (capturable)

    const int threads = 256;
    const int blocks = (int)(B / 512);          // 512 rows per block
    qnet_main<<<blocks, threads, 0, stream>>>(
        x, u1, u2, fc1_w, fc1_b, picker_w, picker_b,
        ew1, eb1, ew2, eb2, out, hard, soft,
        flag_cnt, flag_list, flag_cap);

    qnet_patch<<<128, 256, 0, stream>>>(
        x, u1, u2, fc1_w, fc1_b, picker_w, picker_b,
        ew1, eb1, ew2, eb2, out, hard, soft,
        flag_cnt, flag_list, flag_cap);
}

// Round 17
// 91.840 us; speedup vs baseline: 2.6656x; 1.0034x over previous
//
#include <hip/hip_runtime.h>
#include <math.h>

// Qnet: per-row tiny MLP + gumbel-sigmoid straight-through gates + 5 tiny experts.
//
// Round-16 post-mortem: nt-only stores won 108->92us via L2 effects, but
// FETCH stayed 115MB — `nt` (from __builtin_nontemporal_store) is an
// L2-policy bit; MALL/L3 allocation follows the SCOPE bits. This round,
// ONE change: output stores via inline-asm global_store_dwordx4 with
// `sc0 sc1 nt` (system scope + non-temporal) so writes bypass MALL too.
// If MALL honors it: the 224MB input set fits the 256MB L3 and persists
// across graph replays -> FETCH collapses (<50MB), dur -> 70-85us.
// If FETCH unchanged: MALL is request-immune -> traffic is mandatory ->
// this pattern is at its roofline (~3.4 TB/s for 0.6:1 read:write).
// Tripwire: WRITE > 250MB = amplification -> revert to r16.
//
// Structure (r15/r16): block = 512 rows; u1/u2/x staged coalesced->LDS;
// per-thread 2 rows packed v2f (v_pk_fma); weights via s_load/SGPR;
// exp2-domain gumbel; soft/hard overwrite u1/u2 LDS in place; cooperative
// coalesced stores. Rare |soft-0.5|<2.63e-5 rows -> patch kernel
// (bit-exact CR-f32 numpy simulation, the boundary authority).

constexpr float EPSF = 1e-8f;
constexpr float LN2F = 0.69314718055994531f;
constexpr float T2L  = -2.8853900817779268f;   // -2*log2(e)
constexpr float NL2E = -1.4426950408889634f;   // -log2(e)

typedef float v2f __attribute__((ext_vector_type(2)));
typedef float v4f __attribute__((ext_vector_type(4)));
static __device__ __forceinline__ v2f s2(float s) { return (v2f){s, s}; }
static __device__ __forceinline__ float fexp2(float a) { return __builtin_amdgcn_exp2f(a); }
static __device__ __forceinline__ float flog2(float a) { return __builtin_amdgcn_logf(a); }

// system-scope non-temporal 16B store: bypasses L2 AND MALL allocation
static __device__ __forceinline__ void nts(v4f v, v4f* p) {
    asm volatile("global_store_dwordx4 %0, %1, off sc0 sc1 nt"
                 :: "v"(p), "v"(v) : "memory");
}

__global__ __launch_bounds__(256) void qnet_main(
    const float* __restrict__ x,
    const float* __restrict__ u1,
    const float* __restrict__ u2,
    const float* __restrict__ fc1_w,    // [4][4]
    const float* __restrict__ fc1_b,    // [4]
    const float* __restrict__ picker_w, // [5][4]
    const float* __restrict__ picker_b, // [5]
    const float* __restrict__ ew1,      // [5][4][4]
    const float* __restrict__ eb1,      // [5][4]
    const float* __restrict__ ew2,      // [5][2][4]
    const float* __restrict__ eb2,      // [5][2]
    float* __restrict__ out_o,          // [B][2]
    float* __restrict__ hard_o,         // [B][5]
    float* __restrict__ soft_o,         // [B][5]
    unsigned* __restrict__ flag_cnt,
    unsigned* __restrict__ flag_list,
    unsigned flag_cap)
{
    __shared__ float4 s_u1[640];   // 512 rows * 5 floats; becomes soft
    __shared__ float4 s_u2[640];   // becomes hard
    __shared__ float4 s_x[512];

    const unsigned tid  = threadIdx.x;
    const unsigned row0 = blockIdx.x * 512u;
    const unsigned b5   = blockIdx.x * 640u;   // float4 base into u/soft/hard

    // ---- stage: coalesced global -> LDS ----
    {
        const float4* u14 = reinterpret_cast<const float4*>(u1) + b5;
        const float4* u24 = reinterpret_cast<const float4*>(u2) + b5;
        const float4* x4g = reinterpret_cast<const float4*>(x) + row0;
        s_u1[tid]        = u14[tid];
        s_u1[tid + 256]  = u14[tid + 256];
        s_u2[tid]        = u24[tid];
        s_u2[tid + 256]  = u24[tid + 256];
        s_x[tid]         = x4g[tid];
        s_x[tid + 256]   = x4g[tid + 256];
        if (tid < 128) {
            s_u1[tid + 512] = u14[tid + 512];
            s_u2[tid + 512] = u24[tid + 512];
        }
    }
    __syncthreads();

    // ---- per-thread: rows 2*tid, 2*tid+1 within the block ----
    float* s_u1f = reinterpret_cast<float*>(s_u1);
    float* s_u2f = reinterpret_cast<float*>(s_u2);

    float us1[10], us2[10];
#pragma unroll
    for (int j = 0; j < 10; ++j) {
        us1[j] = s_u1f[10u * tid + j];   // us1[0..4]=row A gates, [5..9]=row B
        us2[j] = s_u2f[10u * tid + j];
    }
    const float4 xa = s_x[2u * tid + 0];
    const float4 xb = s_x[2u * tid + 1];

    v2f xp[4];
    xp[0] = (v2f){xa.x, xb.x}; xp[1] = (v2f){xa.y, xb.y};
    xp[2] = (v2f){xa.z, xb.z}; xp[3] = (v2f){xa.w, xb.w};

    // h = tanh(fc1(x)) — packed FMA, exp2-folded tanh; weights via s_load
    v2f h[4];
#pragma unroll
    for (int j = 0; j < 4; ++j) {
        v2f a = s2(fc1_b[j]);
#pragma unroll
        for (int i = 0; i < 4; ++i) a += xp[i] * s2(fc1_w[4 * j + i]);
        const v2f as = a * s2(T2L);
        const float ex = fexp2(as.x);
        const float ey = fexp2(as.y);
        h[j] = (v2f){fmaf(2.0f, __builtin_amdgcn_rcpf(1.0f + ex), -1.0f),
                     fmaf(2.0f, __builtin_amdgcn_rcpf(1.0f + ey), -1.0f)};
    }

    v2f o0 = s2(0.0f), o1 = s2(0.0f);
    v2f rowmin = s2(1e30f);
    unsigned maskA = 0, maskB = 0;

#pragma unroll
    for (int c = 0; c < 5; ++c) {
        v2f lg = s2(picker_b[c]);
#pragma unroll
        for (int j = 0; j < 4; ++j) lg += h[j] * s2(picker_w[4 * c + j]);

        const v2f a1 = (v2f){us1[c], us1[5 + c]} + s2(EPSF);
        const v2f a2 = (v2f){us2[c], us2[5 + c]} + s2(EPSF);
        // t+eps = fmaf(-ln2, log2(u+eps), eps)
        const v2f t1e = (v2f){fmaf(-LN2F, flog2(a1.x), EPSF),
                              fmaf(-LN2F, flog2(a1.y), EPSF)};
        const v2f t2e = (v2f){fmaf(-LN2F, flog2(a2.x), EPSF),
                              fmaf(-LN2F, flog2(a2.y), EPSF)};
        const v2f lgs = lg * s2(NL2E);
        const v2f epv = (v2f){fexp2(lgs.x), fexp2(lgs.y)} * t1e;
        const v2f den = t2e + epv;
        const v2f sft = t2e * (v2f){__builtin_amdgcn_rcpf(den.x),
                                    __builtin_amdgcn_rcpf(den.y)};
        const v2f hrd = (v2f){(epv.x <= t2e.x) ? 1.0f : 0.0f,
                              (epv.y <= t2e.y) ? 1.0f : 0.0f};

        rowmin = __builtin_elementwise_min(
            rowmin, __builtin_elementwise_abs(sft - s2(0.5f)));
        maskA |= (hrd.x != 0.0f) ? (1u << c) : 0u;
        maskB |= (hrd.y != 0.0f) ? (1u << c) : 0u;

        us1[c] = sft.x; us1[5 + c] = sft.y;   // in place: u1 -> soft
        us2[c] = hrd.x; us2[5 + c] = hrd.y;   // in place: u2 -> hard

        v2f eh[4];
#pragma unroll
        for (int k = 0; k < 4; ++k) {
            v2f a = s2(eb1[4 * c + k]);
#pragma unroll
            for (int j = 0; j < 4; ++j) a += h[j] * s2(ew1[16 * c + 4 * k + j]);
            eh[k] = __builtin_elementwise_max(a, s2(0.0f));
        }
        v2f e0 = s2(eb2[2 * c + 0]);
        v2f e1 = s2(eb2[2 * c + 1]);
#pragma unroll
        for (int k = 0; k < 4; ++k) {
            e0 += eh[k] * s2(ew2[8 * c + 0 + k]);
            e1 += eh[k] * s2(ew2[8 * c + 4 + k]);
        }
        o0 += hrd * e0;
        o1 += hrd * e1;
    }

    // rare flags (soft-domain window; patch recomputes the whole row)
    if (__builtin_expect(rowmin.x < 2.63e-5f, 0)) {
        const unsigned slot = atomicAdd(flag_cnt, 1u);
        if (slot < flag_cap) flag_list[slot] = ((row0 + 2u * tid + 0) << 5) | maskA;
    }
    if (__builtin_expect(rowmin.y < 2.63e-5f, 0)) {
        const unsigned slot = atomicAdd(flag_cnt, 1u);
        if (slot < flag_cap) flag_list[slot] = ((row0 + 2u * tid + 1) << 5) | maskB;
    }

    // write soft/hard back into LDS (in place of u1/u2)
#pragma unroll
    for (int j = 0; j < 10; ++j) {
        s_u1f[10u * tid + j] = us1[j];
        s_u2f[10u * tid + j] = us2[j];
    }

    // out store: coalesced float4, system-scope NT
    {
        v4f* outv = reinterpret_cast<v4f*>(out_o);
        nts((v4f){o0.x, o1.x, o0.y, o1.y}, &outv[blockIdx.x * 256u + tid]);
    }

    __syncthreads();

    // ---- cooperative coalesced LDS -> global stores, system-scope NT ----
    {
        v4f* soft4 = reinterpret_cast<v4f*>(soft_o) + b5;
        v4f* hard4 = reinterpret_cast<v4f*>(hard_o) + b5;
        const v4f* l1 = reinterpret_cast<const v4f*>(s_u1);
        const v4f* l2 = reinterpret_cast<const v4f*>(s_u2);
        nts(l1[tid],       &soft4[tid]);
        nts(l1[tid + 256], &soft4[tid + 256]);
        nts(l2[tid],       &hard4[tid]);
        nts(l2[tid + 256], &hard4[tid + 256]);
        if (tid < 128) {
            nts(l1[tid + 512], &soft4[tid + 512]);
            nts(l2[tid + 512], &hard4[tid + 512]);
        }
    }
}

// ---- rare patch kernel: bit-exact CR-f32 numpy simulation (authority) ----
__global__ __launch_bounds__(256) void qnet_patch(
    const float* __restrict__ x,
    const float* __restrict__ u1,
    const float* __restrict__ u2,
    const float* __restrict__ fc1_w,
    const float* __restrict__ fc1_b,
    const float* __restrict__ picker_w,
    const float* __restrict__ picker_b,
    const float* __restrict__ ew1,
    const float* __restrict__ eb1,
    const float* __restrict__ ew2,
    const float* __restrict__ eb2,
    float* __restrict__ out_o,
    float* __restrict__ hard_o,
    float* __restrict__ soft_o,
    const unsigned* __restrict__ flag_cnt,
    const unsigned* __restrict__ flag_list,
    unsigned flag_cap)
{
    const unsigned n = min(flag_cnt[0], flag_cap);
    const unsigned stride = gridDim.x * blockDim.x;
    for (unsigned i = blockIdx.x * blockDim.x + threadIdx.x; i < n; i += stride) {
        const unsigned e = flag_list[i];
        const unsigned row = e >> 5;
        const unsigned fmask = e & 31u;

        const float4 xv = reinterpret_cast<const float4*>(x)[row];
        const float xr[4] = {xv.x, xv.y, xv.z, xv.w};

        float h32[4];
#pragma unroll
        for (int j = 0; j < 4; ++j) {
            float acc = 0.0f;
#pragma unroll
            for (int i2 = 0; i2 < 4; ++i2)
                acc = fmaf(xr[i2], fc1_w[4 * j + i2], acc);
            const float hpre = acc + fc1_b[j];
            h32[j] = (float)tanh((double)hpre);
        }

        float dout0 = 0.0f, dout1 = 0.0f;
#pragma unroll
        for (int c = 0; c < 5; ++c) {
            const unsigned idx5 = row * 5u + c;
            const float uu1 = u1[idx5];
            const float uu2 = u2[idx5];

            float lacc = 0.0f;
#pragma unroll
            for (int j = 0; j < 4; ++j)
                lacc = fmaf(h32[j], picker_w[4 * c + j], lacc);
            const float lg32 = lacc + picker_b[c];
            const float a1 = uu1 + EPSF;
            const float l1 = (float)log((double)a1);
            const float b1 = (-l1) + EPSF;
            const float g1s = -((float)log((double)b1));
            const float a2 = uu2 + EPSF;
            const float l2 = (float)log((double)a2);
            const float b2 = (-l2) + EPSF;
            const float g2s = -((float)log((double)b2));
            const float dd = g1s - g2s;
            const float z32 = lg32 + dd;
            const float e32 = (float)exp((double)(-z32));
            const float den = 1.0f + e32;
            const float s32 = 1.0f / den;
            const float crhard = (s32 >= 0.5f) ? 1.0f : 0.0f;
            const float fasthard = ((fmask >> c) & 1u) ? 1.0f : 0.0f;

            soft_o[idx5] = s32;
            hard_o[idx5] = crhard;

            if (crhard != fasthard) {
                float eh[4];
#pragma unroll
                for (int k = 0; k < 4; ++k) {
                    float a = eb1[4 * c + k];
#pragma unroll
                    for (int j = 0; j < 4; ++j) a += h32[j] * ew1[16 * c + 4 * k + j];
                    eh[k] = fmaxf(a, 0.0f);
                }
                float e0 = eb2[2 * c + 0];
                float e1 = eb2[2 * c + 1];
#pragma unroll
                for (int k = 0; k < 4; ++k) {
                    e0 += eh[k] * ew2[8 * c + 0 + k];
                    e1 += eh[k] * ew2[8 * c + 4 + k];
                }
                const float d = crhard - fasthard;
                dout0 += d * e0;
                dout1 += d * e1;
            }
        }
        if (dout0 != 0.0f) atomicAdd(&out_o[2u * row + 0], dout0);
        if (dout1 != 0.0f) atomicAdd(&out_o[2u * row + 1], dout1);
    }
}

extern "C" void kernel_launch(void* const* d_in, const int* in_sizes, int n_in,
                              void* d_out, int out_size, void* d_ws, size_t ws_size,
                              hipStream_t stream) {
    const float* x        = (const float*)d_in[0];
    const float* u1       = (const float*)d_in[1];
    const float* u2       = (const float*)d_in[2];
    const float* fc1_w    = (const float*)d_in[3];
    const float* fc1_b    = (const float*)d_in[4];
    const float* picker_w = (const float*)d_in[5];
    const float* picker_b = (const float*)d_in[6];
    const float* ew1      = (const float*)d_in[7];
    const float* eb1      = (const float*)d_in[8];
    const float* ew2      = (const float*)d_in[9];
    const float* eb2      = (const float*)d_in[10];

    const long long B = in_sizes[0] / 4;        // rows
    float* out  = (float*)d_out;                // [B][2]
    float* hard = out + (size_t)B * 2;          // [B][5]
    float* soft = hard + (size_t)B * 5;         // [B][5]

    unsigned* flag_cnt  = (unsigned*)d_ws;
    unsigned* flag_list = flag_cnt + 1;
    const unsigned flag_cap = (unsigned)(ws_size / 4 - 1);

    (void)hipMemsetAsync(d_ws, 0, 4, stream);   // zero the counter (capturable)

    const int threads = 256;
    const int blocks = (int)(B / 512);          // 512 rows per block
    qnet_main<<<blocks, threads, 0, stream>>>(
        x, u1, u2, fc1_w, fc1_b, picker_w, picker_b,
        ew1, eb1, ew2, eb2, out, hard, soft,
        flag_cnt, flag_list, flag_cap);

    qnet_patch<<<128, 256, 0, stream>>>(
        x, u1, u2, fc1_w, fc1_b, picker_w, picker_b,
        ew1, eb1, ew2, eb2, out, hard, soft,
        flag_cnt, flag_list, flag_cap);
}